// Round 3
// baseline (79.094 us; speedup 1.0000x reference)
//
#include <hip/hip_runtime.h>
#include <math.h>

// MultiHeadAttentionQuantum: analytic collapse of the 8-qubit circuit.
//   angles[t][n] = dot(x[t], w_q[n]) + q_params[n] ; c = cos(angles)
//   z[0] = c1..c7 ; z[w>=1] = c0..cw  (Heisenberg CNOT-ring push-through)
//   out[t][e] = sum_n z[n] * w_out[e][n]
//
// R3: R2 was latency-bound (VALU 23%, occ 31%, HBM 32%; steady-state FETCH
// ~2 MB -> x is L3-resident, writes ~100 MB at only 1.8 TB/s). Split into two
// streaming kernels via a 1 MB z scratch: k1 = read-bound dot+cos+prefix,
// k2 = write-bound rank-8 expansion (no shuffles, low VGPR, 8 waves/SIMD).

using f32x4 = __attribute__((ext_vector_type(4))) float;

constexpr int E  = 768;
constexpr int NW = 8;
constexpr int BLOCK = 256;                    // 4 waves
constexpr int TOKENS = 16 * 2048;             // 32768
constexpr int TOK_PER_BLOCK = 16;             // 4 per wave
constexpr int GRID = TOKENS / TOK_PER_BLOCK;  // 2048

__device__ __forceinline__ float dot12(const f32x4& a0, const f32x4& a1, const f32x4& a2,
                                       const f32x4& b0, const f32x4& b1, const f32x4& b2) {
    return a0.x*b0.x + a0.y*b0.y + a0.z*b0.z + a0.w*b0.w
         + a1.x*b1.x + a1.y*b1.y + a1.z*b1.z + a1.w*b1.w
         + a2.x*b2.x + a2.y*b2.y + a2.z*b2.z + a2.w*b2.w;
}

// ---------------- Kernel 1: z[t][n] = circuit(x.w_q + qp) -------------------
__global__ __launch_bounds__(BLOCK, 4)
void zcalc_kernel(const float* __restrict__ x,
                  const float* __restrict__ w_q,
                  const float* __restrict__ q_params,
                  float* __restrict__ zout)          // [TOKENS][NW]
{
    const int tid  = threadIdx.x;
    const int wave = tid >> 6;
    const int lane = tid & 63;
    const int col  = lane * 4;
    const int t0   = blockIdx.x * TOK_PER_BLOCK + wave * 4;

    float qp[NW];
    #pragma unroll
    for (int n = 0; n < NW; ++n) qp[n] = q_params[n];   // uniform -> s_load

    // x: 4 tokens x 3 f32x4 per lane, coalesced, nontemporal (stream once)
    f32x4 xv[4][3];
    #pragma unroll
    for (int tt = 0; tt < 4; ++tt) {
        const f32x4* xp = reinterpret_cast<const f32x4*>(x + (size_t)(t0 + tt) * E);
        #pragma unroll
        for (int k = 0; k < 3; ++k)
            xv[tt][k] = __builtin_nontemporal_load(xp + lane + k * 64);
    }

    float zf[4][NW];
    #pragma unroll
    for (int n = 0; n < NW; ++n) {
        const f32x4* wp = reinterpret_cast<const f32x4*>(w_q + n * E + col);
        const f32x4 w0 = wp[0];
        const f32x4 w1 = wp[64];
        const f32x4 w2 = wp[128];
        #pragma unroll
        for (int tt = 0; tt < 4; ++tt)
            zf[tt][n] = dot12(xv[tt][0], xv[tt][1], xv[tt][2], w0, w1, w2);
    }

    #pragma unroll
    for (int tt = 0; tt < 4; ++tt) {
        float c[NW];
        #pragma unroll
        for (int n = 0; n < NW; ++n) {
            float v = zf[tt][n];
            #pragma unroll
            for (int m = 32; m >= 1; m >>= 1)
                v += __shfl_xor(v, m, 64);
            c[n] = __cosf(v + qp[n]);
        }
        float pref = c[0];
        #pragma unroll
        for (int n = 1; n < NW; ++n) { pref *= c[n]; zf[tt][n] = pref; }  // z_w = c0..cw
        float suf = c[1];
        #pragma unroll
        for (int n = 2; n < NW; ++n) suf *= c[n];
        zf[tt][0] = suf;                                                  // z_0 = c1..c7
    }

    // lane<32 stores zout[t0*8 + lane] = zf[lane>>3][lane&7] -- static
    // cndmask select tree (no dynamic register indexing -> no scratch).
    float sel[NW];
    #pragma unroll
    for (int n = 0; n < NW; ++n) {
        float s01 = (lane & 8)  ? zf[1][n] : zf[0][n];
        float s23 = (lane & 8)  ? zf[3][n] : zf[2][n];
        sel[n]    = (lane & 16) ? s23 : s01;
    }
    float v01 = (lane & 1) ? sel[1] : sel[0];
    float v23 = (lane & 1) ? sel[3] : sel[2];
    float v45 = (lane & 1) ? sel[5] : sel[4];
    float v67 = (lane & 1) ? sel[7] : sel[6];
    float v03 = (lane & 2) ? v23 : v01;
    float v47 = (lane & 2) ? v67 : v45;
    float vv  = (lane & 4) ? v47 : v03;
    if (lane < 32) zout[(size_t)t0 * NW + lane] = vv;   // 128B contiguous / wave
}

// ---------------- Kernel 2: out[t][e] = sum_n z[t][n] * w_out[e][n] ---------
__global__ __launch_bounds__(BLOCK, 8)
void expand_kernel(const float* __restrict__ z,
                   const float* __restrict__ w_out,
                   float* __restrict__ out)
{
    const int tid  = threadIdx.x;
    const int wave = tid >> 6;
    const int lane = tid & 63;
    const int col  = lane * 4;
    const int t0u  = __builtin_amdgcn_readfirstlane(blockIdx.x * TOK_PER_BLOCK + wave * 4);

    // z: 4 tokens x 8 floats, wave-uniform -> scalar loads
    float zz[4][NW];
    #pragma unroll
    for (int tt = 0; tt < 4; ++tt) {
        #pragma unroll
        for (int n = 0; n < NW; ++n)
            zz[tt][n] = z[(size_t)(t0u + tt) * NW + n];
    }

    #pragma unroll
    for (int k = 0; k < 3; ++k) {
        const int e0 = k * 256 + col;          // this lane's 4 output columns
        f32x4 wa[4], wb[4];                    // w_out rows e0..e0+3 (8 floats each)
        #pragma unroll
        for (int e = 0; e < 4; ++e) {
            const f32x4* wp = reinterpret_cast<const f32x4*>(w_out + (size_t)(e0 + e) * NW);
            wa[e] = wp[0];
            wb[e] = wp[1];
        }
        #pragma unroll
        for (int tt = 0; tt < 4; ++tt) {
            f32x4 o;
            #pragma unroll
            for (int e = 0; e < 4; ++e) {
                float v = zz[tt][0] * wa[e].x + zz[tt][1] * wa[e].y
                        + zz[tt][2] * wa[e].z + zz[tt][3] * wa[e].w
                        + zz[tt][4] * wb[e].x + zz[tt][5] * wb[e].y
                        + zz[tt][6] * wb[e].z + zz[tt][7] * wb[e].w;
                if (e == 0) o.x = v; else if (e == 1) o.y = v;
                else if (e == 2) o.z = v; else o.w = v;
            }
            __builtin_nontemporal_store(
                o, reinterpret_cast<f32x4*>(out + (size_t)(t0u + tt) * E + e0));
        }
    }
}

// ---------------- Fallback: fused (R2) if ws too small ----------------------
__global__ __launch_bounds__(BLOCK, 4)
void mhaq_fused(const float* __restrict__ x,
                const float* __restrict__ w_q,
                const float* __restrict__ w_out,
                const float* __restrict__ q_params,
                float* __restrict__ out)
{
    const int tid  = threadIdx.x;
    const int wave = tid >> 6;
    const int lane = tid & 63;
    const int col  = lane * 4;
    const int t0 = blockIdx.x * TOK_PER_BLOCK + wave * 4;

    float qp[NW];
    #pragma unroll
    for (int n = 0; n < NW; ++n) qp[n] = q_params[n];

    f32x4 xv[4][3];
    #pragma unroll
    for (int tt = 0; tt < 4; ++tt) {
        const f32x4* xp = reinterpret_cast<const f32x4*>(x + (size_t)(t0 + tt) * E);
        #pragma unroll
        for (int k = 0; k < 3; ++k)
            xv[tt][k] = __builtin_nontemporal_load(xp + lane + k * 64);
    }
    float zf[4][NW];
    #pragma unroll
    for (int n = 0; n < NW; ++n) {
        const f32x4* wp = reinterpret_cast<const f32x4*>(w_q + n * E + col);
        const f32x4 w0 = wp[0], w1 = wp[64], w2 = wp[128];
        #pragma unroll
        for (int tt = 0; tt < 4; ++tt)
            zf[tt][n] = dot12(xv[tt][0], xv[tt][1], xv[tt][2], w0, w1, w2);
    }
    #pragma unroll
    for (int tt = 0; tt < 4; ++tt) {
        float c[NW];
        #pragma unroll
        for (int n = 0; n < NW; ++n) {
            float v = zf[tt][n];
            #pragma unroll
            for (int m = 32; m >= 1; m >>= 1) v += __shfl_xor(v, m, 64);
            c[n] = __cosf(v + qp[n]);
        }
        float pref = c[0];
        #pragma unroll
        for (int n = 1; n < NW; ++n) { pref *= c[n]; zf[tt][n] = pref; }
        float suf = c[1];
        #pragma unroll
        for (int n = 2; n < NW; ++n) suf *= c[n];
        zf[tt][0] = suf;
    }
    #pragma unroll
    for (int k = 0; k < 3; ++k) {
        const int e0 = k * 256 + col;
        f32x4 wa[4], wb[4];
        #pragma unroll
        for (int e = 0; e < 4; ++e) {
            const f32x4* wp = reinterpret_cast<const f32x4*>(w_out + (size_t)(e0 + e) * NW);
            wa[e] = wp[0]; wb[e] = wp[1];
        }
        #pragma unroll
        for (int tt = 0; tt < 4; ++tt) {
            f32x4 o;
            #pragma unroll
            for (int e = 0; e < 4; ++e) {
                float v = zf[tt][0] * wa[e].x + zf[tt][1] * wa[e].y
                        + zf[tt][2] * wa[e].z + zf[tt][3] * wa[e].w
                        + zf[tt][4] * wb[e].x + zf[tt][5] * wb[e].y
                        + zf[tt][6] * wb[e].z + zf[tt][7] * wb[e].w;
                if (e == 0) o.x = v; else if (e == 1) o.y = v;
                else if (e == 2) o.z = v; else o.w = v;
            }
            __builtin_nontemporal_store(
                o, reinterpret_cast<f32x4*>(out + (size_t)(t0 + tt) * E + e0));
        }
    }
}

extern "C" void kernel_launch(void* const* d_in, const int* in_sizes, int n_in,
                              void* d_out, int out_size, void* d_ws, size_t ws_size,
                              hipStream_t stream) {
    const float* x        = (const float*)d_in[0];
    const float* w_q      = (const float*)d_in[1];
    const float* w_out    = (const float*)d_in[2];
    const float* q_params = (const float*)d_in[3];
    float* out = (float*)d_out;

    const size_t z_bytes = (size_t)TOKENS * NW * sizeof(float);
    if (ws_size >= z_bytes) {
        float* z = (float*)d_ws;
        hipLaunchKernelGGL(zcalc_kernel,  dim3(GRID), dim3(BLOCK), 0, stream,
                           x, w_q, q_params, z);
        hipLaunchKernelGGL(expand_kernel, dim3(GRID), dim3(BLOCK), 0, stream,
                           z, w_out, out);
    } else {
        hipLaunchKernelGGL(mhaq_fused, dim3(GRID), dim3(BLOCK), 0, stream,
                           x, w_q, w_out, q_params, out);
    }
}